// Round 1
// baseline (346.563 us; speedup 1.0000x reference)
//
#include <hip/hip_runtime.h>
#include <hip/hip_bf16.h>

// Problem: x (16,256,32,32) fp32, weight (8193,256) fp32 (emb = first 8192 rows).
// Rows: r = b*1024 + (h*32+w), xf[r][c] = x[b*262144 + c*1024 + (r&1023)].
// Outputs (flat fp32): xq (4194304) | loss (1) | code-as-float (16384).

#define N_ROWS   16384
#define KCODES   8192
#define DIM      256
#define LOSS_OFF 4194304
#define CODE_OFF 4194305
#define MARGIN   0.01f

typedef _Float16 half8  __attribute__((ext_vector_type(8)));
typedef _Float16 half4v __attribute__((ext_vector_type(4)));
typedef float    float4v __attribute__((ext_vector_type(4)));

__device__ __forceinline__ unsigned mono(float f) {
  unsigned u = __float_as_uint(f);
  return u ^ (unsigned)(((int)u >> 31) | 0x80000000);
}
__device__ __forceinline__ float unmono(unsigned m) {
  unsigned u = (m & 0x80000000u) ? (m ^ 0x80000000u) : ~m;
  return __uint_as_float(u);
}
__device__ __forceinline__ unsigned long long umin64(unsigned long long a, unsigned long long b) {
  return a < b ? a : b;
}
// merge top-2 {b,s} with top-2 {ob,os} (packed u64s, smaller = better)
__device__ __forceinline__ void merge2(unsigned long long& b, unsigned long long& s,
                                       unsigned long long ob, unsigned long long os) {
  if (ob < b) { s = umin64(b, os); b = ob; }
  else        { s = umin64(s, ob); }
}

// ---------------------------------------------------------------- prep x -> xh (f16, row-major [row][c])
__global__ __launch_bounds__(256) void k_prep_x(const float* __restrict__ x, _Float16* __restrict__ xh) {
  int t   = threadIdx.x;
  int blk = blockIdx.x;            // 256 blocks x 64 rows
  int row = t & 63;
  int cq  = t >> 6;                // 0..3
  int r   = blk * 64 + row;
  int b   = r >> 10;
  int n   = r & 1023;
  const float* xb = x + (size_t)b * 262144 + n;
  for (int j = 0; j < 16; ++j) {
    int c0 = (cq + 4 * j) * 4;     // float4 group over c
    half4v h;
#pragma unroll
    for (int i = 0; i < 4; ++i) h[i] = (_Float16)xb[(size_t)(c0 + i) * 1024];
    *(half4v*)&xh[(size_t)r * DIM + c0] = h;
  }
}

// ---------------------------------------------------------------- prep emb -> eh (f16) + ||e||^2
__global__ __launch_bounds__(64) void k_prep_e(const float* __restrict__ w, _Float16* __restrict__ eh,
                                               float* __restrict__ en2) {
  int k = blockIdx.x, lane = threadIdx.x;
  float4v v = *(const float4v*)&w[(size_t)k * DIM + lane * 4];
  half4v h;
  float s = 0.f;
#pragma unroll
  for (int i = 0; i < 4; ++i) { h[i] = (_Float16)v[i]; s = fmaf(v[i], v[i], s); }
  *(half4v*)&eh[(size_t)k * DIM + lane * 4] = h;
#pragma unroll
  for (int d = 32; d; d >>= 1) s += __shfl_xor(s, d);
  if (lane == 0) en2[k] = s;
}

// ---------------------------------------------------------------- main GEMM + top-2 epilogue
#define BM 128
#define BN 256
#define LDT 72   // padded LDS stride in halves (64 + 8, keeps 16B alignment, breaks bank aliasing)

__global__ __launch_bounds__(512) void k_gemm(const _Float16* __restrict__ xh, const _Float16* __restrict__ eh,
                                              const float* __restrict__ en2,
                                              unsigned long long* __restrict__ top2) {
  __shared__ __align__(16) _Float16 As[BM * LDT];
  __shared__ __align__(16) _Float16 Bs[BN * LDT];
  int t    = threadIdx.x;
  int bx   = blockIdx.x;   // code tile 0..31 (256 codes)
  int by   = blockIdx.y;   // row tile  0..127 (128 rows)
  int lane = t & 63, w = t >> 6;
  int wr = w & 1, wc = w >> 1;          // wave tile: rows 64*wr, codes 64*wc
  int ln15 = lane & 15, q = lane >> 4;

  float4v acc[4][4];
#pragma unroll
  for (int mi = 0; mi < 4; ++mi)
#pragma unroll
    for (int ni = 0; ni < 4; ++ni) acc[mi][ni] = (float4v){0.f, 0.f, 0.f, 0.f};

  const uint4* xh4 = (const uint4*)(xh + (size_t)by * BM * DIM);  // 32 uint4 per row
  const uint4* eh4 = (const uint4*)(eh + (size_t)bx * BN * DIM);

  for (int ch = 0; ch < 4; ++ch) {      // K chunks of 64
    if (ch) __syncthreads();
    for (int u = t; u < BM * 8; u += 512) {          // A: 128 rows x 8 uint4
      int row = u >> 3, cu = u & 7;
      *(uint4*)&As[row * LDT + cu * 8] = xh4[row * 32 + ch * 8 + cu];
    }
    for (int u = t; u < BN * 8; u += 512) {          // B: 256 codes x 8 uint4
      int row = u >> 3, cu = u & 7;
      *(uint4*)&Bs[row * LDT + cu * 8] = eh4[row * 32 + ch * 8 + cu];
    }
    __syncthreads();
#pragma unroll
    for (int ks = 0; ks < 2; ++ks) {
      half8 a[4], bf[4];
#pragma unroll
      for (int mi = 0; mi < 4; ++mi)
        a[mi] = *(const half8*)&As[(wr * 64 + mi * 16 + ln15) * LDT + ks * 32 + q * 8];
#pragma unroll
      for (int ni = 0; ni < 4; ++ni)
        bf[ni] = *(const half8*)&Bs[(wc * 64 + ni * 16 + ln15) * LDT + ks * 32 + q * 8];
#pragma unroll
      for (int mi = 0; mi < 4; ++mi)
#pragma unroll
        for (int ni = 0; ni < 4; ++ni)
          acc[mi][ni] = __builtin_amdgcn_mfma_f32_16x16x32_f16(a[mi], bf[ni], acc[mi][ni], 0, 0, 0);
    }
  }

  // epilogue: per-row top-2 over this block's 256 codes
  int k0 = bx * 256 + wc * 64;
  float en[4];
#pragma unroll
  for (int ni = 0; ni < 4; ++ni) en[ni] = en2[k0 + ni * 16 + ln15];

  __syncthreads();                       // all frag reads done; reuse As as epilogue buffer
  unsigned long long* ep = (unsigned long long*)(void*)As;   // [128 rows][4 wc][2]

#pragma unroll
  for (int mi = 0; mi < 4; ++mi) {
#pragma unroll
    for (int r = 0; r < 4; ++r) {
      unsigned long long p[4];
#pragma unroll
      for (int ni = 0; ni < 4; ++ni) {
        float s = fmaf(-2.f, acc[mi][ni][r], en[ni]);   // ||e||^2 - 2 x.e
        int kg  = k0 + ni * 16 + ln15;
        p[ni] = ((unsigned long long)mono(s) << 32) | (unsigned)kg;
      }
      unsigned long long b0 = umin64(p[0], p[1]);
      unsigned long long s0 = p[0] ^ p[1] ^ b0;         // max(p0,p1)
      if (p[2] < b0) { s0 = b0; b0 = p[2]; } else if (p[2] < s0) s0 = p[2];
      if (p[3] < b0) { s0 = b0; b0 = p[3]; } else if (p[3] < s0) s0 = p[3];
#pragma unroll
      for (int d = 1; d < 16; d <<= 1) {
        unsigned long long ob = __shfl_xor(b0, d);
        unsigned long long os = __shfl_xor(s0, d);
        merge2(b0, s0, ob, os);
      }
      if (ln15 == 0) {
        int rl = wr * 64 + mi * 16 + q * 4 + r;
        ep[rl * 8 + wc * 2 + 0] = b0;
        ep[rl * 8 + wc * 2 + 1] = s0;
      }
    }
  }
  __syncthreads();
  if (t < 128) {
    unsigned long long b0 = ep[t * 8 + 0], s0 = ep[t * 8 + 1];
#pragma unroll
    for (int j = 1; j < 4; ++j) merge2(b0, s0, ep[t * 8 + 2 * j], ep[t * 8 + 2 * j + 1]);
    size_t rowg = (size_t)by * BM + t;
    top2[rowg * 64 + bx * 2 + 0] = b0;
    top2[rowg * 64 + bx * 2 + 1] = s0;
  }
}

// ---------------------------------------------------------------- refine: exact fp64 argmin over candidates
__global__ __launch_bounds__(256) void k_refine(const unsigned long long* __restrict__ top2,
                                                const float* __restrict__ x, const float* __restrict__ w,
                                                int* __restrict__ code, float* __restrict__ out) {
  int t = threadIdx.x, lane = t & 63, wv = t >> 6;
  int row = blockIdx.x * 4 + wv;
  unsigned long long mine = top2[(size_t)row * 64 + lane];
  unsigned long long mn = mine;
#pragma unroll
  for (int d = 1; d < 64; d <<= 1) mn = umin64(mn, __shfl_xor(mn, d));
  float mf = unmono((unsigned)(mn >> 32));
  float sf = unmono((unsigned)(mine >> 32));
  unsigned long long bal = __ballot(sf <= mf + MARGIN);
  int kbest;
  if (__popcll(bal) <= 1) {
    kbest = (int)(unsigned)(mn & 0xffffffffULL);     // unique candidate: it is the argmin
  } else {
    int b = row >> 10, n = row & 1023;
    const float* xr = x + (size_t)b * 262144 + n;
    float4v ex;
#pragma unroll
    for (int i = 0; i < 4; ++i) ex[i] = xr[(size_t)(lane * 4 + i) * 1024];
    double bs = 1e300; int bk = 0x7fffffff;
    while (bal) {
      int l = __ffsll((unsigned long long)bal) - 1;
      bal &= bal - 1;
      int kc = (int)(unsigned)(__shfl(mine, l) & 0xffffffffULL);
      float4v wv4 = *(const float4v*)&w[(size_t)kc * DIM + lane * 4];
      double s = 0.0;
#pragma unroll
      for (int i = 0; i < 4; ++i) { double e = (double)wv4[i]; s += e * (e - 2.0 * (double)ex[i]); }
#pragma unroll
      for (int d = 1; d < 64; d <<= 1) s += __shfl_xor(s, d);
      if (s < bs || (s == bs && kc < bk)) { bs = s; bk = kc; }
    }
    kbest = bk;
  }
  if (lane == 0) { code[row] = kbest; out[CODE_OFF + row] = (float)kbest; }
}

// ---------------------------------------------------------------- gather xq + loss partials
__global__ __launch_bounds__(256) void k_out(const int* __restrict__ code, const float* __restrict__ w,
                                             const float* __restrict__ x, float* __restrict__ out,
                                             float* __restrict__ lacc) {
  __shared__ float ec[32 * 261];       // 32 rows x 256 c, stride 261 (odd -> conflict-free col reads)
  __shared__ int   cds[32];
  __shared__ float part[4];
  int t   = threadIdx.x;
  int blk = blockIdx.x;                // 512 blocks x 32 rows
  int row0 = blk * 32;
  int b = row0 >> 10, n0 = row0 & 1023;
  if (t < 32) cds[t] = code[row0 + t];
  __syncthreads();
  {
    int rr = t >> 6;                   // 0..3
    int c4 = (t & 63) * 4;
    for (int j = 0; j < 8; ++j) {
      int r = rr + 4 * j;
      float4v v = *(const float4v*)&w[(size_t)cds[r] * DIM + c4];
#pragma unroll
      for (int i = 0; i < 4; ++i) ec[r * 261 + c4 + i] = v[i];
    }
  }
  __syncthreads();
  float ls = 0.f;
  int r2 = t & 31;
  int cg = t >> 5;                     // 0..7
  const size_t base = (size_t)b * 262144 + n0 + r2;
  for (int j = 0; j < 32; ++j) {
    int c = cg * 32 + j;
    float v  = ec[r2 * 261 + c];
    size_t a = base + (size_t)c * 1024;
    float xv = x[a];
    out[a] = v;
    float d = v - xv;
    ls = fmaf(d, d, ls);
  }
#pragma unroll
  for (int d = 32; d; d >>= 1) ls += __shfl_xor(ls, d);
  if ((t & 63) == 0) part[t >> 6] = ls;
  __syncthreads();
  if (t == 0) atomicAdd(lacc, part[0] + part[1] + part[2] + part[3]);
}

__global__ void k_loss(const float* __restrict__ lacc, float* __restrict__ out) {
  out[LOSS_OFF] = 1.25f * (*lacc) / 4194304.0f;
}

// ---------------------------------------------------------------- launch
extern "C" void kernel_launch(void* const* d_in, const int* in_sizes, int n_in,
                              void* d_out, int out_size, void* d_ws, size_t ws_size,
                              hipStream_t stream) {
  const float* x = (const float*)d_in[0];
  const float* w = (const float*)d_in[1];
  float* out = (float*)d_out;
  char* ws = (char*)d_ws;
  // ws layout (bytes): xh 8,388,608 | eh 4,194,304 | en2 32,768 | top2 8,388,608 | code 65,536 | loss 4
  _Float16* xh  = (_Float16*)(ws);
  _Float16* eh  = (_Float16*)(ws + 8388608);
  float*    en2 = (float*)(ws + 12582912);
  unsigned long long* top2 = (unsigned long long*)(ws + 12615680);
  int*   code = (int*)(ws + 21004288);
  float* lacc = (float*)(ws + 21069824);

  hipMemsetAsync(lacc, 0, 4, stream);
  k_prep_x<<<256, 256, 0, stream>>>(x, xh);
  k_prep_e<<<KCODES, 64, 0, stream>>>(w, eh, en2);
  k_gemm<<<dim3(32, 128), 512, 0, stream>>>(xh, eh, en2, top2);
  k_refine<<<4096, 256, 0, stream>>>(top2, x, w, code, out);
  k_out<<<512, 256, 0, stream>>>(code, w, x, out, lacc);
  k_loss<<<1, 1, 0, stream>>>(lacc, out);
}

// Round 2
// 262.644 us; speedup vs baseline: 1.3195x; 1.3195x over previous
//
#include <hip/hip_runtime.h>
#include <hip/hip_bf16.h>

// Problem: x (16,256,32,32) fp32, weight (8193,256) fp32 (emb = first 8192 rows).
// Rows: r = b*1024 + (h*32+w), xf[r][c] = x[b*262144 + c*1024 + (r&1023)].
// Outputs (flat fp32): xq (4194304) | loss (1) | code-as-float (16384).
//
// R2: m97-style GEMM — 128x128 tile, 4 waves, BK=64, global_load_lds(16B),
// XOR-swizzled global tile layout (pre-swizzled in prep kernels) so staging is
// an identity copy AND fragment ds_read_b128 is 2-way-max (free) on banks.
// top2 candidate lists (128 u64/row = 16 MB) live in d_out's xq region, which
// k_out overwrites afterwards.

#define N_ROWS   16384
#define KCODES   8192
#define DIM      256
#define LOSS_OFF 4194304
#define CODE_OFF 4194305
#define MARGIN   0.01f

typedef _Float16 half8  __attribute__((ext_vector_type(8)));
typedef _Float16 half4v __attribute__((ext_vector_type(4)));
typedef float    float4v __attribute__((ext_vector_type(4)));

__device__ __forceinline__ unsigned mono(float f) {
  unsigned u = __float_as_uint(f);
  return u ^ (unsigned)(((int)u >> 31) | 0x80000000);
}
__device__ __forceinline__ float unmono(unsigned m) {
  unsigned u = (m & 0x80000000u) ? (m ^ 0x80000000u) : ~m;
  return __uint_as_float(u);
}
__device__ __forceinline__ unsigned long long umin64(unsigned long long a, unsigned long long b) {
  return a < b ? a : b;
}
__device__ __forceinline__ void merge2(unsigned long long& b, unsigned long long& s,
                                       unsigned long long ob, unsigned long long os) {
  if (ob < b) { s = umin64(b, os); b = ob; }
  else        { s = umin64(s, ob); }
}
__device__ __forceinline__ void gll16(const _Float16* g, _Float16* l) {
  __builtin_amdgcn_global_load_lds((const __attribute__((address_space(1))) void*)g,
                                   (__attribute__((address_space(3))) void*)l, 16, 0, 0);
}

// Swizzled tile layout (both xh and eh): per 128-row tile, per 64-half chunk,
// 16B unit u = row_local*8 + (kgrp ^ (row_local & 7)); tile chunk = 8192 halves.

// ---------------------------------------------------------------- prep x -> xh (f16, swizzled tiles)
__global__ __launch_bounds__(256) void k_prep_x(const float* __restrict__ x, _Float16* __restrict__ xh) {
  int t   = threadIdx.x;
  int blk = blockIdx.x;            // 256 blocks x 64 rows
  int row = t & 63;
  int s   = t >> 6;                // 0..3
  int r   = blk * 64 + row;
  int b   = r >> 10;
  int n   = r & 1023;
  const float* xb = x + (size_t)b * 262144 + n;
  int r7 = r & 7, rl = r & 127;
  size_t tb = (size_t)(r >> 7) * 32768;       // 4 chunks x 8192 halves per row-tile
  for (int j = 0; j < 8; ++j) {
    int g = s + 4 * j;             // c-group 0..31 (8 halves each)
    int chunk = g >> 3, kg = g & 7;
    half8 h;
#pragma unroll
    for (int i = 0; i < 8; ++i) h[i] = (_Float16)xb[(size_t)(g * 8 + i) * 1024];
    int p = kg ^ r7;
    *(half8*)&xh[tb + (size_t)chunk * 8192 + rl * 64 + p * 8] = h;
  }
}

// ---------------------------------------------------------------- prep emb -> eh (swizzled) + ||e||^2
__global__ __launch_bounds__(256) void k_prep_e(const float* __restrict__ wt, _Float16* __restrict__ eh,
                                                float* __restrict__ en2) {
  __shared__ __align__(16) _Float16 ls[8192];   // 32 codes x 256 halves
  __shared__ float es[32];
  int t = threadIdx.x;
  int k0 = blockIdx.x * 32;                     // 256 blocks x 32 codes
  if (t < 32) es[t] = 0.f;
  __syncthreads();
  const float* wb = wt + (size_t)k0 * 256;
  for (int i = 0; i < 8; ++i) {
    int lin = i * 1024 + t * 4;                 // coalesced float4 over 8192
    float4v v = *(const float4v*)&wb[lin];
    half4v h; float ss = 0.f;
#pragma unroll
    for (int j = 0; j < 4; ++j) { h[j] = (_Float16)v[j]; ss = fmaf(v[j], v[j], ss); }
    *(half4v*)&ls[lin] = h;
    atomicAdd(&es[lin >> 8], ss);
  }
  __syncthreads();
  size_t tb = (size_t)(k0 >> 7) * 32768;
  for (int i = 0; i < 4; ++i) {
    int u = i * 256 + t;                        // 1024 16B units = 32 codes x 32
    int code_l = u >> 5;
    int cu = u & 31, chunk = cu >> 3, p = cu & 7;
    int kgl = k0 + code_l;
    int kg = p ^ (kgl & 7);
    half8 h = *(half8*)&ls[code_l * 256 + chunk * 64 + kg * 8];
    *(half8*)&eh[tb + (size_t)chunk * 8192 + (size_t)(kgl & 127) * 64 + p * 8] = h;
  }
  if (t < 32) en2[k0 + t] = es[t];
}

// ---------------------------------------------------------------- main GEMM + top-2 epilogue
__global__ __launch_bounds__(256) void k_gemm(const _Float16* __restrict__ xh, const _Float16* __restrict__ eh,
                                              const float* __restrict__ en2,
                                              unsigned long long* __restrict__ top2) {
  __shared__ __align__(16) _Float16 As[8192];   // 128 rows x 64 halves, swizzled image
  __shared__ __align__(16) _Float16 Bs[8192];
  int t    = threadIdx.x;
  int bx   = blockIdx.x;   // code tile 0..63 (128 codes)
  int by   = blockIdx.y;   // row tile  0..127 (128 rows)
  int lane = t & 63, w = t >> 6;
  int wr = w & 1, wc = w >> 1;                  // wave tile 64x64
  int ln15 = lane & 15, q = lane >> 4;

  const _Float16* Ag = xh + (size_t)by * 32768;
  const _Float16* Bg = eh + (size_t)bx * 32768;

  float4v acc[4][4];
#pragma unroll
  for (int mi = 0; mi < 4; ++mi)
#pragma unroll
    for (int ni = 0; ni < 4; ++ni) acc[mi][ni] = (float4v){0.f, 0.f, 0.f, 0.f};

  int so = (w * 64 + lane) * 8;                 // per-lane staging source offset (halves)
  int lo = w * 512;                             // per-wave LDS dest offset (halves)

  for (int ch = 0; ch < 4; ++ch) {
    if (ch) __syncthreads();
    const _Float16* ac = Ag + ch * 8192;
    const _Float16* bc = Bg + ch * 8192;
#pragma unroll
    for (int i = 0; i < 4; ++i) {
      gll16(ac + i * 2048 + so, As + i * 2048 + lo);
      gll16(bc + i * 2048 + so, Bs + i * 2048 + lo);
    }
    __syncthreads();
#pragma unroll
    for (int ks = 0; ks < 2; ++ks) {
      half8 af[4], bf[4];
#pragma unroll
      for (int mi = 0; mi < 4; ++mi) {
        int row = wr * 64 + mi * 16 + ln15;
        af[mi] = *(const half8*)&As[(row * 8 + ((ks * 4 + q) ^ (row & 7))) * 8];
      }
#pragma unroll
      for (int ni = 0; ni < 4; ++ni) {
        int row = wc * 64 + ni * 16 + ln15;
        bf[ni] = *(const half8*)&Bs[(row * 8 + ((ks * 4 + q) ^ (row & 7))) * 8];
      }
#pragma unroll
      for (int mi = 0; mi < 4; ++mi)
#pragma unroll
        for (int ni = 0; ni < 4; ++ni)
          acc[mi][ni] = __builtin_amdgcn_mfma_f32_16x16x32_f16(af[mi], bf[ni], acc[mi][ni], 0, 0, 0);
    }
  }

  // epilogue: per-row top-2 over this block's 128 codes
  int k0 = bx * 128 + wc * 64;
  float en[4];
#pragma unroll
  for (int ni = 0; ni < 4; ++ni) en[ni] = en2[k0 + ni * 16 + ln15];

  __syncthreads();                              // frag reads done; reuse As
  unsigned long long* ep = (unsigned long long*)(void*)As;   // [128 rows][2 wc][2]

#pragma unroll
  for (int mi = 0; mi < 4; ++mi) {
#pragma unroll
    for (int r = 0; r < 4; ++r) {
      unsigned long long p[4];
#pragma unroll
      for (int ni = 0; ni < 4; ++ni) {
        float s = fmaf(-2.f, acc[mi][ni][r], en[ni]);   // ||e||^2 - 2 x.e
        p[ni] = ((unsigned long long)mono(s) << 32) | (unsigned)(k0 + ni * 16 + ln15);
      }
      unsigned long long b0 = umin64(p[0], p[1]);
      unsigned long long s0 = p[0] ^ p[1] ^ b0;
      if (p[2] < b0) { s0 = b0; b0 = p[2]; } else if (p[2] < s0) s0 = p[2];
      if (p[3] < b0) { s0 = b0; b0 = p[3]; } else if (p[3] < s0) s0 = p[3];
#pragma unroll
      for (int d = 1; d < 16; d <<= 1) {
        unsigned long long ob = __shfl_xor(b0, d);
        unsigned long long os = __shfl_xor(s0, d);
        merge2(b0, s0, ob, os);
      }
      if (ln15 == 0) {
        int rl = wr * 64 + mi * 16 + q * 4 + r;
        ep[rl * 4 + wc * 2 + 0] = b0;
        ep[rl * 4 + wc * 2 + 1] = s0;
      }
    }
  }
  __syncthreads();
  if (t < 128) {
    unsigned long long b0 = ep[t * 4 + 0], s0 = ep[t * 4 + 1];
    merge2(b0, s0, ep[t * 4 + 2], ep[t * 4 + 3]);
    size_t rowg = (size_t)by * 128 + t;
    top2[rowg * 128 + bx * 2 + 0] = b0;
    top2[rowg * 128 + bx * 2 + 1] = s0;
  }
}

// ---------------------------------------------------------------- refine: exact fp64 argmin over candidates
__global__ __launch_bounds__(256) void k_refine(const unsigned long long* __restrict__ top2,
                                                const float* __restrict__ x, const float* __restrict__ w,
                                                int* __restrict__ code, float* __restrict__ out) {
  int t = threadIdx.x, lane = t & 63, wv = t >> 6;
  int row = blockIdx.x * 4 + wv;
  const unsigned long long* tr = top2 + (size_t)row * 128;
  unsigned long long e0 = tr[2 * lane], e1 = tr[2 * lane + 1];
  unsigned long long mn = umin64(e0, e1);
#pragma unroll
  for (int d = 1; d < 64; d <<= 1) mn = umin64(mn, __shfl_xor(mn, d));
  float mf = unmono((unsigned)(mn >> 32));
  bool c0 = unmono((unsigned)(e0 >> 32)) <= mf + MARGIN;
  bool c1 = unmono((unsigned)(e1 >> 32)) <= mf + MARGIN;
  unsigned long long bal0 = __ballot(c0), bal1 = __ballot(c1);
  int kbest;
  if (__popcll(bal0) + __popcll(bal1) <= 1) {
    kbest = (int)(unsigned)(mn & 0xffffffffULL);
  } else {
    int b = row >> 10, n = row & 1023;
    const float* xr = x + (size_t)b * 262144 + n;
    float4v ex;
#pragma unroll
    for (int i = 0; i < 4; ++i) ex[i] = xr[(size_t)(lane * 4 + i) * 1024];
    double bs = 1e300; int bk = 0x7fffffff;
    for (int pass = 0; pass < 2; ++pass) {
      unsigned long long bal = pass ? bal1 : bal0;
      unsigned long long src = pass ? e1 : e0;
      while (bal) {
        int l = __ffsll((unsigned long long)bal) - 1;
        bal &= bal - 1;
        int kc = (int)(unsigned)(__shfl(src, l) & 0xffffffffULL);
        float4v wv4 = *(const float4v*)&w[(size_t)kc * DIM + lane * 4];
        double s = 0.0;
#pragma unroll
        for (int i = 0; i < 4; ++i) { double e = (double)wv4[i]; s += e * (e - 2.0 * (double)ex[i]); }
#pragma unroll
        for (int d = 1; d < 64; d <<= 1) s += __shfl_xor(s, d);
        if (s < bs || (s == bs && kc < bk)) { bs = s; bk = kc; }
      }
    }
    kbest = bk;
  }
  if (lane == 0) { code[row] = kbest; out[CODE_OFF + row] = (float)kbest; }
}

// ---------------------------------------------------------------- gather xq + loss partials
__global__ __launch_bounds__(256) void k_out(const int* __restrict__ code, const float* __restrict__ w,
                                             const float* __restrict__ x, float* __restrict__ out,
                                             float* __restrict__ lacc) {
  __shared__ float ec[32 * 261];
  __shared__ int   cds[32];
  __shared__ float part[4];
  int t   = threadIdx.x;
  int blk = blockIdx.x;                // 512 blocks x 32 rows
  int row0 = blk * 32;
  int b = row0 >> 10, n0 = row0 & 1023;
  if (t < 32) cds[t] = code[row0 + t];
  __syncthreads();
  {
    int rr = t >> 6;
    int c4 = (t & 63) * 4;
    for (int j = 0; j < 8; ++j) {
      int r = rr + 4 * j;
      float4v v = *(const float4v*)&w[(size_t)cds[r] * DIM + c4];
#pragma unroll
      for (int i = 0; i < 4; ++i) ec[r * 261 + c4 + i] = v[i];
    }
  }
  __syncthreads();
  float ls = 0.f;
  int r2 = t & 31;
  int cg = t >> 5;
  const size_t base = (size_t)b * 262144 + n0 + r2;
  for (int j = 0; j < 32; ++j) {
    int c = cg * 32 + j;
    float v  = ec[r2 * 261 + c];
    size_t a = base + (size_t)c * 1024;
    float xv = x[a];
    out[a] = v;
    float d = v - xv;
    ls = fmaf(d, d, ls);
  }
#pragma unroll
  for (int d = 32; d; d >>= 1) ls += __shfl_xor(ls, d);
  if ((t & 63) == 0) part[t >> 6] = ls;
  __syncthreads();
  if (t == 0) atomicAdd(lacc, part[0] + part[1] + part[2] + part[3]);
}

__global__ void k_loss(const float* __restrict__ lacc, float* __restrict__ out) {
  out[LOSS_OFF] = 1.25f * (*lacc) / 4194304.0f;
}

// ---------------------------------------------------------------- launch
extern "C" void kernel_launch(void* const* d_in, const int* in_sizes, int n_in,
                              void* d_out, int out_size, void* d_ws, size_t ws_size,
                              hipStream_t stream) {
  const float* x = (const float*)d_in[0];
  const float* w = (const float*)d_in[1];
  float* out = (float*)d_out;
  char* ws = (char*)d_ws;
  // ws layout (bytes): xh 8,388,608 | eh 4,194,304 | en2 32,768 | code 65,536 | lacc 4
  _Float16* xh  = (_Float16*)(ws);
  _Float16* eh  = (_Float16*)(ws + 8388608);
  float*    en2 = (float*)(ws + 12582912);
  int*      codep = (int*)(ws + 12615680);
  float*    lacc  = (float*)(ws + 12681216);
  // top2 candidates (16384 rows x 128 u64 = 16 MB) live in d_out's xq region;
  // k_out overwrites that region afterwards.
  unsigned long long* top2 = (unsigned long long*)d_out;

  hipMemsetAsync(lacc, 0, 4, stream);
  k_prep_x<<<256, 256, 0, stream>>>(x, xh);
  k_prep_e<<<256, 256, 0, stream>>>(w, eh, en2);
  k_gemm<<<dim3(64, 128), 256, 0, stream>>>(xh, eh, en2, top2);
  k_refine<<<4096, 256, 0, stream>>>(top2, x, w, codep, out);
  k_out<<<512, 256, 0, stream>>>(codep, w, x, out, lacc);
  k_loss<<<1, 1, 0, stream>>>(lacc, out);
}

// Round 3
// 185.714 us; speedup vs baseline: 1.8661x; 1.4142x over previous
//
#include <hip/hip_runtime.h>
#include <hip/hip_bf16.h>

// Problem: x (16,256,32,32) fp32, weight (8193,256) fp32 (emb = first 8192 rows).
// Rows: r = b*1024 + (h*32+w), xf[r][c] = x[b*262144 + c*1024 + (r&1023)].
// Outputs (flat fp32): xq (4194304) | loss (1) | code-as-float (16384).
//
// R3: transposed GEMM (A=codes, B=xrows) so per-lane acc values share an
// x-row -> lane-local top-2. C-init folds (32 - 0.5*||e||^2): acc is a
// positive biased score, raw IEEE bits are order-preserving, packed with a
// 6-bit local code index into one u32. Max-form argmin, margin 0.005 (acc
// units) = 0.01 in d2 units; exact fp64 refine unchanged.

#define N_ROWS   16384
#define KCODES   8192
#define DIM      256
#define LOSS_OFF 4194304
#define CODE_OFF 4194305
#define MARGIN_ACC 0.005f

typedef _Float16 half8  __attribute__((ext_vector_type(8)));
typedef _Float16 half4v __attribute__((ext_vector_type(4)));
typedef float    float4v __attribute__((ext_vector_type(4)));
typedef unsigned long long u64;

__device__ __forceinline__ unsigned umax32(unsigned a, unsigned b) { return a > b ? a : b; }
__device__ __forceinline__ unsigned umin32(unsigned a, unsigned b) { return a < b ? a : b; }
__device__ __forceinline__ u64 umax64(u64 a, u64 b) { return a > b ? a : b; }
__device__ __forceinline__ u64 umin64(u64 a, u64 b) { return a < b ? a : b; }
__device__ __forceinline__ void gll16(const _Float16* g, _Float16* l) {
  __builtin_amdgcn_global_load_lds((const __attribute__((address_space(1))) void*)g,
                                   (__attribute__((address_space(3))) void*)l, 16, 0, 0);
}

// Swizzled tile layout (xh and eh): per 128-row tile, per 64-half K-chunk,
// 16B unit u = row_local*8 + (kgrp ^ (row_local & 7)); chunk = 8192 halves.

// ---------------------------------------------------------------- prep x -> xh (f16, swizzled tiles)
__global__ __launch_bounds__(256) void k_prep_x(const float* __restrict__ x, _Float16* __restrict__ xh) {
  int t   = threadIdx.x;
  int blk = blockIdx.x;            // 256 blocks x 64 rows
  int row = t & 63;
  int s   = t >> 6;                // 0..3
  int r   = blk * 64 + row;
  int b   = r >> 10;
  int n   = r & 1023;
  const float* xb = x + (size_t)b * 262144 + n;
  int r7 = r & 7, rl = r & 127;
  size_t tb = (size_t)(r >> 7) * 32768;
  for (int j = 0; j < 8; ++j) {
    int g = s + 4 * j;             // c-group 0..31 (8 halves each)
    int chunk = g >> 3, kg = g & 7;
    half8 h;
#pragma unroll
    for (int i = 0; i < 8; ++i) h[i] = (_Float16)xb[(size_t)(g * 8 + i) * 1024];
    int p = kg ^ r7;
    *(half8*)&xh[tb + (size_t)chunk * 8192 + rl * 64 + p * 8] = h;
  }
}

// ---------------------------------------------------------------- prep emb -> eh (swizzled) + 32-0.5*||e||^2
__global__ __launch_bounds__(256) void k_prep_e(const float* __restrict__ wt, _Float16* __restrict__ eh,
                                                float* __restrict__ en2c) {
  __shared__ __align__(16) _Float16 ls[8192];   // 32 codes x 256 halves
  __shared__ float es[32];
  int t = threadIdx.x;
  int k0 = blockIdx.x * 32;                     // 256 blocks x 32 codes
  if (t < 32) es[t] = 0.f;
  __syncthreads();
  const float* wb = wt + (size_t)k0 * 256;
  for (int i = 0; i < 8; ++i) {
    int lin = i * 1024 + t * 4;
    float4v v = *(const float4v*)&wb[lin];
    half4v h; float ss = 0.f;
#pragma unroll
    for (int j = 0; j < 4; ++j) { h[j] = (_Float16)v[j]; ss = fmaf(v[j], v[j], ss); }
    *(half4v*)&ls[lin] = h;
    atomicAdd(&es[lin >> 8], ss);
  }
  __syncthreads();
  size_t tb = (size_t)(k0 >> 7) * 32768;
  for (int i = 0; i < 4; ++i) {
    int u = i * 256 + t;
    int code_l = u >> 5;
    int cu = u & 31, chunk = cu >> 3, p = cu & 7;
    int kgl = k0 + code_l;
    int kg = p ^ (kgl & 7);
    half8 h = *(half8*)&ls[code_l * 256 + chunk * 64 + kg * 8];
    *(half8*)&eh[tb + (size_t)chunk * 8192 + (size_t)(kgl & 127) * 64 + p * 8] = h;
  }
  if (t < 32) en2c[k0 + t] = 32.0f - 0.5f * es[t];
}

// ---------------------------------------------------------------- main GEMM (A=codes, B=xrows) + top-2 epilogue
__global__ __launch_bounds__(256) void k_gemm(const _Float16* __restrict__ xh, const _Float16* __restrict__ eh,
                                              const float* __restrict__ en2c,
                                              u64* __restrict__ top2) {
  __shared__ __align__(16) _Float16 As[8192];   // 128 codes x 64 halves (swizzled)
  __shared__ __align__(16) _Float16 Bs[8192];   // 128 xrows x 64 halves (swizzled)
  int t    = threadIdx.x;
  int bx   = blockIdx.x;   // code tile 0..63 (128 codes)
  int by   = blockIdx.y;   // xrow tile 0..127 (128 rows)
  int lane = t & 63, w = t >> 6;
  int wr = w & 1, wc = w >> 1;                  // wave: codes 64*wr, xrows 64*wc
  int ln15 = lane & 15, q = lane >> 4;
  int q4 = q * 4;

  const _Float16* Ag = eh + (size_t)bx * 32768;
  const _Float16* Bg = xh + (size_t)by * 32768;

  int kwave = bx * 128 + wr * 64;
  float4v cin[4];
#pragma unroll
  for (int mi = 0; mi < 4; ++mi) cin[mi] = *(const float4v*)&en2c[kwave + mi * 16 + q4];

  float4v acc[4][4];
#pragma unroll
  for (int mi = 0; mi < 4; ++mi)
#pragma unroll
    for (int ni = 0; ni < 4; ++ni) acc[mi][ni] = cin[mi];

  int so = (w * 64 + lane) * 8;                 // staging source offset (halves)
  int lo = w * 512;                             // per-wave LDS dest offset (halves)

  for (int ch = 0; ch < 4; ++ch) {
    if (ch) __syncthreads();
    const _Float16* ac = Ag + ch * 8192;
    const _Float16* bc = Bg + ch * 8192;
#pragma unroll
    for (int i = 0; i < 4; ++i) {
      gll16(ac + i * 2048 + so, As + i * 2048 + lo);
      gll16(bc + i * 2048 + so, Bs + i * 2048 + lo);
    }
    __syncthreads();
#pragma unroll
    for (int ks = 0; ks < 2; ++ks) {
      half8 af[4], bf[4];
#pragma unroll
      for (int mi = 0; mi < 4; ++mi) {
        int row = wr * 64 + mi * 16 + ln15;     // code row
        af[mi] = *(const half8*)&As[(row * 8 + ((ks * 4 + q) ^ (row & 7))) * 8];
      }
#pragma unroll
      for (int ni = 0; ni < 4; ++ni) {
        int row = wc * 64 + ni * 16 + ln15;     // xrow
        bf[ni] = *(const half8*)&Bs[(row * 8 + ((ks * 4 + q) ^ (row & 7))) * 8];
      }
#pragma unroll
      for (int mi = 0; mi < 4; ++mi)
#pragma unroll
        for (int ni = 0; ni < 4; ++ni)
          acc[mi][ni] = __builtin_amdgcn_mfma_f32_16x16x32_f16(af[mi], bf[ni], acc[mi][ni], 0, 0, 0);
    }
  }

  // epilogue: per x-row top-2 (max of biased acc) over this wave's 64 codes.
  // acc[mi][ni][r]: code_local = mi*16 + q*4 + r, xrow = wc*64 + ni*16 + ln15.
  __syncthreads();                              // frag reads done; reuse As
  u64* ep = (u64*)(void*)As;                    // [128 xrows][2 wr][2]

#pragma unroll
  for (int ni = 0; ni < 4; ++ni) {
    unsigned hi[8], lo2[8];
#pragma unroll
    for (int j = 0; j < 8; ++j) {               // pair (mi, r=2j?) -> flatten: pair regs r=0/1, r=2/3
      int mi = j >> 1, rb = (j & 1) * 2;
      unsigned p0 = (__float_as_uint(acc[mi][ni][rb])     & 0xFFFFFFC0u) | (unsigned)(mi * 16 + q4 + rb);
      unsigned p1 = (__float_as_uint(acc[mi][ni][rb + 1]) & 0xFFFFFFC0u) | (unsigned)(mi * 16 + q4 + rb + 1);
      hi[j] = umax32(p0, p1); lo2[j] = umin32(p0, p1);
    }
#pragma unroll
    for (int st = 4; st; st >>= 1)              // merge sorted pairs: 8->4->2->1
#pragma unroll
      for (int j = 0; j < 8; ++j) if (j < st) {
        unsigned nb = umax32(hi[j], hi[j + st]);
        unsigned ns = umax32(umin32(hi[j], hi[j + st]), umax32(lo2[j], lo2[j + st]));
        hi[j] = nb; lo2[j] = ns;
      }
    unsigned b = hi[0], s = lo2[0];
#pragma unroll
    for (int d = 16; d < 64; d <<= 1) {         // cross-quad merge (4 lanes hold same xrow)
      unsigned ob = __shfl_xor(b, d);
      unsigned os = __shfl_xor(s, d);
      unsigned ns = umax32(umin32(b, ob), umax32(s, os));
      b = umax32(b, ob); s = ns;
    }
    if (q == 0) {
      int rl = wc * 64 + ni * 16 + ln15;
      ep[rl * 4 + wr * 2 + 0] = ((u64)b << 32) | (unsigned)(kwave + (b & 63));
      ep[rl * 4 + wr * 2 + 1] = ((u64)s << 32) | (unsigned)(kwave + (s & 63));
    }
  }
  __syncthreads();
  if (t < 128) {
    u64 a0 = ep[t * 4 + 0], a1 = ep[t * 4 + 1], b0 = ep[t * 4 + 2], b1 = ep[t * 4 + 3];
    u64 nb = umax64(a0, b0);
    u64 ns = umax64(umin64(a0, b0), umax64(a1, b1));
    size_t rowg = (size_t)by * 128 + t;
    top2[rowg * 128 + bx * 2 + 0] = nb;
    top2[rowg * 128 + bx * 2 + 1] = ns;
  }
}

// ---------------------------------------------------------------- refine: exact fp64 argmin over candidates
__global__ __launch_bounds__(256) void k_refine(const u64* __restrict__ top2,
                                                const float* __restrict__ x, const float* __restrict__ w,
                                                int* __restrict__ code, float* __restrict__ out) {
  int t = threadIdx.x, lane = t & 63, wv = t >> 6;
  int row = blockIdx.x * 4 + wv;
  const u64* tr = top2 + (size_t)row * 128;
  u64 e0 = tr[2 * lane], e1 = tr[2 * lane + 1];
  u64 mx = umax64(e0, e1);
#pragma unroll
  for (int d = 1; d < 64; d <<= 1) mx = umax64(mx, __shfl_xor(mx, d));
  float fm = __uint_as_float((unsigned)(mx >> 32) & 0xFFFFFFC0u);   // biased -0.5*d2 (max)
  bool c0 = __uint_as_float((unsigned)(e0 >> 32) & 0xFFFFFFC0u) >= fm - MARGIN_ACC;
  bool c1 = __uint_as_float((unsigned)(e1 >> 32) & 0xFFFFFFC0u) >= fm - MARGIN_ACC;
  u64 bal0 = __ballot(c0), bal1 = __ballot(c1);
  int kbest;
  if (__popcll(bal0) + __popcll(bal1) <= 1) {
    kbest = (int)(unsigned)(mx & 0xffffffffULL);
  } else {
    int b = row >> 10, n = row & 1023;
    const float* xr = x + (size_t)b * 262144 + n;
    float4v ex;
#pragma unroll
    for (int i = 0; i < 4; ++i) ex[i] = xr[(size_t)(lane * 4 + i) * 1024];
    double bs = 1e300; int bk = 0x7fffffff;
    for (int pass = 0; pass < 2; ++pass) {
      u64 bal = pass ? bal1 : bal0;
      u64 src = pass ? e1 : e0;
      while (bal) {
        int l = __ffsll((unsigned long long)bal) - 1;
        bal &= bal - 1;
        int kc = (int)(unsigned)(__shfl(src, l) & 0xffffffffULL);
        float4v wv4 = *(const float4v*)&w[(size_t)kc * DIM + lane * 4];
        double s = 0.0;
#pragma unroll
        for (int i = 0; i < 4; ++i) { double e = (double)wv4[i]; s += e * (e - 2.0 * (double)ex[i]); }
#pragma unroll
        for (int d = 1; d < 64; d <<= 1) s += __shfl_xor(s, d);
        if (s < bs || (s == bs && kc < bk)) { bs = s; bk = kc; }
      }
    }
    kbest = bk;
  }
  if (lane == 0) { code[row] = kbest; out[CODE_OFF + row] = (float)kbest; }
}

// ---------------------------------------------------------------- gather xq + loss partials
__global__ __launch_bounds__(256) void k_out(const int* __restrict__ code, const float* __restrict__ w,
                                             const float* __restrict__ x, float* __restrict__ out,
                                             float* __restrict__ lacc) {
  __shared__ float ec[32 * 261];
  __shared__ int   cds[32];
  __shared__ float part[4];
  int t   = threadIdx.x;
  int blk = blockIdx.x;                // 512 blocks x 32 rows
  int row0 = blk * 32;
  int b = row0 >> 10, n0 = row0 & 1023;
  if (t < 32) cds[t] = code[row0 + t];
  __syncthreads();
  {
    int rr = t >> 6;
    int c4 = (t & 63) * 4;
    for (int j = 0; j < 8; ++j) {
      int r = rr + 4 * j;
      float4v v = *(const float4v*)&w[(size_t)cds[r] * DIM + c4];
#pragma unroll
      for (int i = 0; i < 4; ++i) ec[r * 261 + c4 + i] = v[i];
    }
  }
  __syncthreads();
  float ls = 0.f;
  int r2 = t & 31;
  int cg = t >> 5;
  const size_t base = (size_t)b * 262144 + n0 + r2;
  for (int j = 0; j < 32; ++j) {
    int c = cg * 32 + j;
    float v  = ec[r2 * 261 + c];
    size_t a = base + (size_t)c * 1024;
    float xv = x[a];
    out[a] = v;
    float d = v - xv;
    ls = fmaf(d, d, ls);
  }
#pragma unroll
  for (int d = 32; d; d >>= 1) ls += __shfl_xor(ls, d);
  if ((t & 63) == 0) part[t >> 6] = ls;
  __syncthreads();
  if (t == 0) atomicAdd(lacc, part[0] + part[1] + part[2] + part[3]);
}

__global__ void k_loss(const float* __restrict__ lacc, float* __restrict__ out) {
  out[LOSS_OFF] = 1.25f * (*lacc) / 4194304.0f;
}

// ---------------------------------------------------------------- launch
extern "C" void kernel_launch(void* const* d_in, const int* in_sizes, int n_in,
                              void* d_out, int out_size, void* d_ws, size_t ws_size,
                              hipStream_t stream) {
  const float* x = (const float*)d_in[0];
  const float* w = (const float*)d_in[1];
  float* out = (float*)d_out;
  char* ws = (char*)d_ws;
  _Float16* xh  = (_Float16*)(ws);                  // 8,388,608 B
  _Float16* eh  = (_Float16*)(ws + 8388608);        // 4,194,304 B
  float*    en2c = (float*)(ws + 12582912);         // 32,768 B
  int*      codep = (int*)(ws + 12615680);          // 65,536 B
  float*    lacc  = (float*)(ws + 12681216);        // 4 B
  u64*      top2  = (u64*)d_out;                    // 16 MB in xq region (overwritten by k_out)

  hipMemsetAsync(lacc, 0, 4, stream);
  k_prep_x<<<256, 256, 0, stream>>>(x, xh);
  k_prep_e<<<256, 256, 0, stream>>>(w, eh, en2c);
  k_gemm<<<dim3(64, 128), 256, 0, stream>>>(xh, eh, en2c, top2);
  k_refine<<<4096, 256, 0, stream>>>(top2, x, w, codep, out);
  k_out<<<512, 256, 0, stream>>>(codep, w, x, out, lacc);
  k_loss<<<1, 1, 0, stream>>>(lacc, out);
}